// Round 12
// baseline (41.182 us; speedup 1.0000x reference)
//
#include <hip/hip_runtime.h>
#include <hip/hip_bf16.h>

#define D_DIM 256
#define K_CODES 1024
#define N_ROWS (32 * 1024)
#define BLOCK_ROWS 64                 // rows per block
#define NBLK (N_ROWS / BLOCK_ROWS)    // 512 blocks = 2/CU
#define STEPS 8                       // 64-code tiles per code-half

typedef __attribute__((ext_vector_type(4))) float f32x4;
typedef __attribute__((ext_vector_type(2))) long i64x2;
typedef long i64;

#define MFMA8 __builtin_amdgcn_mfma_f32_16x16x32_fp8_fp8
#define CVT8 __builtin_amdgcn_cvt_pk_fp8_f32

static __device__ __forceinline__ void gload_lds16(const void* g, void* s) {
    __builtin_amdgcn_global_load_lds(
        (const __attribute__((address_space(1))) void*)g,
        (__attribute__((address_space(3))) void*)s, 16, 0, 0);
}

static __device__ __forceinline__ i64 pack_fp8x8(float4 p, float4 q, float S) {
    int w0 = CVT8(p.x * S, p.y * S, 0, false);
    w0     = CVT8(p.z * S, p.w * S, w0, true);
    int w1 = CVT8(q.x * S, q.y * S, 0, false);
    w1     = CVT8(q.z * S, q.w * S, w1, true);
    return ((i64)(unsigned)w1 << 32) | (unsigned)w0;
}

// ---------------------------------------------------------------- prep
// (a) enorm[k] = ||E[k]||^2 (f32, exact E);
// (b) Eb8 = fp8(-1024*E) in MFMA B-frag order, kk-PAIRED for b128 reads:
//     i64 idx(tile16,kk,l) = tile16*512 + (kk>>1)*128 + l*2 + (kk&1)
//     holds E[code = tile16*16 + (l&15)][d = kk*32 + (l>>4)*8 + j] at byte j.
__global__ __launch_bounds__(256) void vq_prep(const float* __restrict__ E,
                                               float* __restrict__ enorm,
                                               i64* __restrict__ Eb8) {
    int wave = threadIdx.x >> 6;
    int lane = threadIdx.x & 63;
    int k = blockIdx.x * 4 + wave;               // [0,1024)
    const float4 v = *reinterpret_cast<const float4*>(E + k * D_DIM + lane * 4);
    float s = v.x * v.x + v.y * v.y + v.z * v.z + v.w * v.w;
    #pragma unroll
    for (int off = 32; off; off >>= 1) s += __shfl_xor(s, off, 64);
    if (lane == 0) enorm[k] = s;

    if (blockIdx.x < 128) {
        int g = blockIdx.x * 256 + threadIdx.x;  // [0, 32768)
        int t = g >> 9;
        int kk = (g >> 6) & 7;
        int l = g & 63;
        int code = t * 16 + (l & 15);
        int d0 = kk * 32 + ((l >> 4) << 3);
        const float* src = E + (size_t)code * D_DIM + d0;
        float4 v0 = *reinterpret_cast<const float4*>(src);
        float4 v1 = *reinterpret_cast<const float4*>(src + 4);
        Eb8[t * 512 + ((kk >> 1) << 7) + l * 2 + (kk & 1)] =
            pack_fp8x8(v0, v1, -1024.0f);
    }
}

// ---------------------------------------------------------------- main
// 512 blocks (2/CU) x 256 thr. Wave (rg,ch): rows [rg*32,+32) (2 MFMA
// chains), codes [ch*512,+512) in 8 tiles of 64 codes (16 KB fp8).
// Per-half ping-pong LDS tiles; stage(t+1) at step top, vmcnt(0) drain at
// step END (free: full step >> L2 latency; also orders cross-wave DMA
// before the barrier). 8 barriers total. Fused epilogue: merge code-half
// pairs in LDS, gather f32 E (exact output), loss = minval + |x|^2.
__global__ __launch_bounds__(256, 2) void vq_main(const float* __restrict__ X,
                                                  const float* __restrict__ E,
                                                  const float* __restrict__ enorm,
                                                  const i64* __restrict__ Eb8,
                                                  float* __restrict__ outq,
                                                  float* __restrict__ lpart) {
    __shared__ i64   Bh[2][2][2048];   // [ch][buf][16KB tile] = 64 KB
    __shared__ float En[1024];         // 4 KB
    __shared__ float mvs[2][BLOCK_ROWS];
    __shared__ int   mis[2][BLOCK_ROWS];
    __shared__ float fxn[BLOCK_ROWS];
    __shared__ float wsum[4];

    const int tid = threadIdx.x;
    const int w   = tid >> 6;
    const int rg  = w & 1;        // row half
    const int ch  = w >> 1;       // code half
    const int l   = tid & 63;
    const int lr  = l & 15;
    const int lk  = l >> 4;
    const int brow0 = blockIdx.x * BLOCK_ROWS;
    const int row0  = brow0 + rg * 32;

    // each wave stages ITS half-tile portion: 8 x 16B/lane = 8 KB/wave
#define STAGE(T)                                                              \
    do {                                                                      \
        const size_t src0 = (size_t)ch * 16384 + (size_t)(T) * 2048           \
                          + rg * 1024 + l * 2;                                \
        i64* dst0 = &Bh[ch][(T) & 1][rg * 1024 + l * 2];                      \
        _Pragma("unroll")                                                     \
        for (int it = 0; it < 8; ++it)                                        \
            gload_lds16(Eb8 + src0 + it * 128, dst0 + it * 128);              \
    } while (0)

    STAGE(0);                                     // overlaps the X prologue
    gload_lds16(enorm + tid * 4, &En[tid * 4]);   // 1 load/wave, uniform cnt

    // ---- prologue: 32 rows of X -> fp8 A-frags (2 rowsets) + row norms
    i64   a[2][8];
    float xn[2] = {0.f, 0.f};
    #pragma unroll
    for (int s = 0; s < 2; ++s) {
        const float* xp = X + (size_t)(row0 + s * 16 + lr) * D_DIM + lk * 8;
        #pragma unroll
        for (int kk = 0; kk < 8; ++kk) {
            float4 p = *reinterpret_cast<const float4*>(xp + kk * 32);
            float4 q = *reinterpret_cast<const float4*>(xp + kk * 32 + 4);
            xn[s] += p.x * p.x + p.y * p.y + p.z * p.z + p.w * p.w
                   + q.x * q.x + q.y * q.y + q.z * q.z + q.w * q.w;
            a[s][kk] = pack_fp8x8(p, q, 1.0f);
        }
        xn[s] += __shfl_xor(xn[s], 16, 64);
        xn[s] += __shfl_xor(xn[s], 32, 64);   // lanes 0-15: norm of row lr
    }

    float minv[2][4];
    int   mini[2][4];
    #pragma unroll
    for (int s = 0; s < 2; ++s)
        #pragma unroll
        for (int i = 0; i < 4; ++i) { minv[s][i] = INFINITY; mini[s][i] = 0; }

    asm volatile("s_waitcnt vmcnt(0)" ::: "memory");   // tile 0 + En landed
    __builtin_amdgcn_sched_barrier(0);
    __builtin_amdgcn_s_barrier();

    const float inv = 1.0f / 512.0f;   // undo -1024 scale -> -2 x.e

    #pragma unroll 1
    for (int t = 0; t < STEPS; ++t) {
        if (t < STEPS - 1) STAGE(t + 1);
        __builtin_amdgcn_sched_barrier(0);

        const int buf = t & 1;
        #pragma unroll
        for (int ct = 0; ct < 4; ++ct) {
            i64x2 bp[4];
            #pragma unroll
            for (int p = 0; p < 4; ++p)
                bp[p] = *reinterpret_cast<const i64x2*>(
                    &Bh[ch][buf][ct * 512 + p * 128 + l * 2]);

            f32x4 acc0 = {0, 0, 0, 0}, acc1 = {0, 0, 0, 0};
            #pragma unroll
            for (int kk = 0; kk < 8; ++kk) {
                const i64 b = bp[kk >> 1][kk & 1];
                acc0 = MFMA8(a[0][kk], b, acc0, 0, 0, 0);
                acc1 = MFMA8(a[1][kk], b, acc1, 0, 0, 0);
            }

            const int tt16 = ch * 32 + t * 4 + ct;     // global 16-code tile
            const float en = En[tt16 * 16 + lr];
            const int idx  = tt16 * 16 + lr;
            #pragma unroll
            for (int i = 0; i < 4; ++i) {
                float s0 = fmaf(acc0[i], inv, en);
                float s1 = fmaf(acc1[i], inv, en);
                if (s0 < minv[0][i]) { minv[0][i] = s0; mini[0][i] = idx; }
                if (s1 < minv[1][i]) { minv[1][i] = s1; mini[1][i] = idx; }
            }
        }

        // drain this step's prefetch (free: full step >> L2 latency) and
        // seal the buffer swap; also orders the other wave's DMA writes.
        asm volatile("s_waitcnt vmcnt(0)" ::: "memory");
        __builtin_amdgcn_sched_barrier(0);
        __builtin_amdgcn_s_barrier();
    }
#undef STAGE

    // ---- reduce over the 16 code-lanes (first-min tie-break, butterfly)
    #pragma unroll
    for (int off = 8; off >= 1; off >>= 1) {
        #pragma unroll
        for (int s = 0; s < 2; ++s)
            #pragma unroll
            for (int i = 0; i < 4; ++i) {
                float ov = __shfl_xor(minv[s][i], off, 64);
                int   oi = __shfl_xor(mini[s][i], off, 64);
                if (ov < minv[s][i] || (ov == minv[s][i] && oi < mini[s][i])) {
                    minv[s][i] = ov; mini[s][i] = oi;
                }
            }
    }

    // ---- publish per-wave results
    if (ch == 0 && l < 16) {
        fxn[rg * 32 + l]      = xn[0];
        fxn[rg * 32 + 16 + l] = xn[1];
    }
    if (lr == 0) {
        #pragma unroll
        for (int s = 0; s < 2; ++s)
            #pragma unroll
            for (int i = 0; i < 4; ++i) {
                const int r = rg * 32 + s * 16 + lk * 4 + i;
                mvs[ch][r] = minv[s][i];
                mis[ch][r] = mini[s][i];
            }
    }
    __syncthreads();

    // ---- merge halves + gather E[idx] -> outq (wave w: rows [w*16,+16))
    #pragma unroll 4
    for (int rr = 0; rr < 16; ++rr) {
        const int r = w * 16 + rr;
        // ch0 indices < ch1 indices: strict < keeps first-occurrence min
        const int idx = (mvs[1][r] < mvs[0][r]) ? mis[1][r] : mis[0][r];
        const float4 qv = *reinterpret_cast<const float4*>(
            E + (size_t)idx * D_DIM + l * 4);
        f32x4 tv = {qv.x, qv.y, qv.z, qv.w};
        __builtin_nontemporal_store(
            tv, reinterpret_cast<f32x4*>(outq + (size_t)(brow0 + r) * D_DIM + l * 4));
    }

    // ---- loss: sum over this wave's 16 rows of (minval + xnorm)
    float v = 0.0f;
    if (l < 16) {
        const int r = w * 16 + l;
        v = fminf(mvs[0][r], mvs[1][r]) + fxn[r];
    }
    #pragma unroll
    for (int off = 32; off; off >>= 1) v += __shfl_xor(v, off, 64);
    if (l == 0) wsum[w] = v;
    __syncthreads();
    if (tid == 0)
        lpart[blockIdx.x] = wsum[0] + wsum[1] + wsum[2] + wsum[3];
}

// ---------------------------------------------------------------- finalize
// deterministic fold of 512 block partials -> vq_loss scalar
__global__ __launch_bounds__(256) void vq_finalize(const float* __restrict__ partials,
                                                   float* __restrict__ out_loss) {
    __shared__ float s[256];
    int t = threadIdx.x;
    s[t] = partials[t] + partials[t + 256];
    __syncthreads();
    #pragma unroll
    for (int off = 128; off; off >>= 1) {
        if (t < off) s[t] += s[t + off];
        __syncthreads();
    }
    if (t == 0)
        out_loss[0] = s[0] * (1.25f / (float)((size_t)N_ROWS * D_DIM));
}

// ---------------------------------------------------------------- launch
extern "C" void kernel_launch(void* const* d_in, const int* in_sizes, int n_in,
                              void* d_out, int out_size, void* d_ws, size_t ws_size,
                              hipStream_t stream) {
    const float* X = (const float*)d_in[0];   // latents  [32768, 256] f32
    const float* E = (const float*)d_in[1];   // codebook [1024, 256]  f32
    float* out = (float*)d_out;               // 8388608 quantized + 1 loss

    float* enorm = (float*)d_ws;                          // 1024 f32
    float* lpart = enorm + K_CODES;                       // 512 f32 (1024 slot)
    i64*   Eb8   = (i64*)(lpart + 1024);                  // 256 KB fp8 frags

    vq_prep    <<<256,  256, 0, stream>>>(E, enorm, Eb8);
    vq_main    <<<NBLK, 256, 0, stream>>>(X, E, enorm, Eb8, out, lpart);
    vq_finalize<<<1,    256, 0, stream>>>(lpart, out + (size_t)N_ROWS * D_DIM);
}

// Round 13
// 40.638 us; speedup vs baseline: 1.0134x; 1.0134x over previous
//
#include <hip/hip_runtime.h>
#include <hip/hip_bf16.h>

#define D_DIM 256
#define K_CODES 1024
#define N_ROWS (32 * 1024)
#define BLOCK_ROWS 32                 // rows per block (2 rg x 16)
#define NBLK (N_ROWS / BLOCK_ROWS)    // 1024 blocks -> 4/CU
#define STEPS 32                      // 16-code fp8 tiles per kg (512 codes)
#define TILE_I64 520                  // 512 frag i64 (4KB) + 8 i64 (en 64B)

typedef __attribute__((ext_vector_type(4))) float f32x4;
typedef __attribute__((ext_vector_type(2))) long i64x2;
typedef long i64;

#define MFMA8 __builtin_amdgcn_mfma_f32_16x16x32_fp8_fp8
#define CVT8 __builtin_amdgcn_cvt_pk_fp8_f32

static __device__ __forceinline__ void gload_lds16(const void* g, void* s) {
    __builtin_amdgcn_global_load_lds(
        (const __attribute__((address_space(1))) void*)g,
        (__attribute__((address_space(3))) void*)s, 16, 0, 0);
}
static __device__ __forceinline__ void gload_lds4(const void* g, void* s) {
    __builtin_amdgcn_global_load_lds(
        (const __attribute__((address_space(1))) void*)g,
        (__attribute__((address_space(3))) void*)s, 4, 0, 0);
}

static __device__ __forceinline__ i64 pack_fp8x8(float4 p, float4 q, float S) {
    int w0 = CVT8(p.x * S, p.y * S, 0, false);
    w0     = CVT8(p.z * S, p.w * S, w0, true);
    int w1 = CVT8(q.x * S, q.y * S, 0, false);
    w1     = CVT8(q.z * S, q.w * S, w1, true);
    return ((i64)(unsigned)w1 << 32) | (unsigned)w0;
}

// ---------------------------------------------------------------- prep
// (a) enorm[k] = ||E[k]||^2 (f32 exact); (b) Eb8 = fp8(-1024*E), B-frag
// order, kk-PAIRED: i64 idx(t16,kk,l) = t16*512 + (kk>>1)*128 + l*2 + (kk&1)
__global__ __launch_bounds__(256) void vq_prep(const float* __restrict__ E,
                                               float* __restrict__ enorm,
                                               i64* __restrict__ Eb8) {
    int wave = threadIdx.x >> 6;
    int lane = threadIdx.x & 63;
    int k = blockIdx.x * 4 + wave;               // [0,1024)
    const float4 v = *reinterpret_cast<const float4*>(E + k * D_DIM + lane * 4);
    float s = v.x * v.x + v.y * v.y + v.z * v.z + v.w * v.w;
    #pragma unroll
    for (int off = 32; off; off >>= 1) s += __shfl_xor(s, off, 64);
    if (lane == 0) enorm[k] = s;

    if (blockIdx.x < 128) {
        int g = blockIdx.x * 256 + threadIdx.x;  // [0, 32768)
        int t = g >> 9;
        int kk = (g >> 6) & 7;
        int l = g & 63;
        int code = t * 16 + (l & 15);
        int d0 = kk * 32 + ((l >> 4) << 3);
        const float* src = E + (size_t)code * D_DIM + d0;
        float4 v0 = *reinterpret_cast<const float4*>(src);
        float4 v1 = *reinterpret_cast<const float4*>(src + 4);
        Eb8[t * 512 + ((kk >> 1) << 7) + l * 2 + (kk & 1)] =
            pack_fp8x8(v0, v1, -1024.0f);
    }
}

// ---------------------------------------------------------------- main
// 1024 blocks (4/CU, 16 waves/CU) x 256 thr. Wave (kg,rg): rows
// [rg*16,+16) x codes [kg*512,+512) in 32 fp8 tiles of 16 codes (4 KB).
// rg pair co-stages each kg tile (3 uniform loads/wave: 2 frag + en) into
// a ring-3 LDS buffer, prefetched 2 ahead; counted vmcnt(3) + 1 barrier
// per step. 4 resident blocks cover residual stalls. Fused epilogue.
__global__ __launch_bounds__(256, 4) void vq_main(const float* __restrict__ X,
                                                  const float* __restrict__ E,
                                                  const float* __restrict__ enorm,
                                                  const i64* __restrict__ Eb8,
                                                  float* __restrict__ outq,
                                                  float* __restrict__ lpart) {
    __shared__ i64   Bt[2][3][TILE_I64];   // ~24.4 KB
    __shared__ float mvs[2][BLOCK_ROWS];
    __shared__ int   mis[2][BLOCK_ROWS];
    __shared__ float fxn[BLOCK_ROWS];

    const int tid = threadIdx.x;
    const int w   = tid >> 6;
    const int kg  = w >> 1;       // code half
    const int rg  = w & 1;        // row half
    const int l   = tid & 63;
    const int lr  = l & 15;
    const int lk  = l >> 4;
    const int row0 = blockIdx.x * BLOCK_ROWS;
    const int rowb = row0 + rg * 16;

    // 3 uniform loads/wave/stage: 2 frag KB (rg split) + en (dup by rg)
#define STAGE(T)                                                              \
    do {                                                                      \
        const int t16_ = kg * STEPS + (T);                                    \
        i64* bb = &Bt[kg][(T) % 3][0];                                        \
        _Pragma("unroll")                                                     \
        for (int it = 0; it < 2; ++it) {                                      \
            const int seg = rg * 2 + it;                                      \
            gload_lds16(Eb8 + (size_t)t16_ * 512 + seg * 128 + l * 2,         \
                        bb + seg * 128);                                      \
        }                                                                     \
        if (l < 16) gload_lds4(enorm + t16_ * 16 + l, bb + 512);              \
    } while (0)

    STAGE(0);
    STAGE(1);

    // ---- prologue: 16 rows of X -> fp8 A-frags + f32 row norms
    i64   a[8];
    float xn = 0.0f;
    {
        const float* xp = X + (size_t)(rowb + lr) * D_DIM + lk * 8;
        #pragma unroll
        for (int kk = 0; kk < 8; ++kk) {
            float4 p = *reinterpret_cast<const float4*>(xp + kk * 32);
            float4 q = *reinterpret_cast<const float4*>(xp + kk * 32 + 4);
            xn += p.x * p.x + p.y * p.y + p.z * p.z + p.w * p.w
                + q.x * q.x + q.y * q.y + q.z * q.z + q.w * q.w;
            a[kk] = pack_fp8x8(p, q, 1.0f);
        }
        xn += __shfl_xor(xn, 16, 64);
        xn += __shfl_xor(xn, 32, 64);   // all lanes: norm of row rowb+lr
    }

    float minv[4];
    int   mini[4];
    #pragma unroll
    for (int i = 0; i < 4; ++i) { minv[i] = INFINITY; mini[i] = 0; }

    const float inv = 1.0f / 512.0f;   // undo -1024 scale -> -2 x.e

    #pragma unroll 1
    for (int t = 0; t < STEPS; ++t) {
        if (t < STEPS - 1) { asm volatile("s_waitcnt vmcnt(3)" ::: "memory"); }
        else               { asm volatile("s_waitcnt vmcnt(0)" ::: "memory"); }
        __builtin_amdgcn_sched_barrier(0);
        __builtin_amdgcn_s_barrier();   // both rg halves of tile t landed

        const int buf = t % 3;
        i64x2 bp[4];
        #pragma unroll
        for (int p = 0; p < 4; ++p)
            bp[p] = *reinterpret_cast<const i64x2*>(&Bt[kg][buf][p * 128 + l * 2]);
        const float en = reinterpret_cast<const float*>(&Bt[kg][buf][512])[lr];

        if (t < STEPS - 2) STAGE(t + 2);   // into buf (t+2)%3 = (t-1)%3

        f32x4 acc = {0, 0, 0, 0};
        #pragma unroll
        for (int kk = 0; kk < 8; ++kk)
            acc = MFMA8(a[kk], bp[kk >> 1][kk & 1], acc, 0, 0, 0);

        const int idx = (kg * STEPS + t) * 16 + lr;
        #pragma unroll
        for (int i = 0; i < 4; ++i) {
            float s = fmaf(acc[i], inv, en);
            if (s < minv[i]) { minv[i] = s; mini[i] = idx; }
        }
        __builtin_amdgcn_sched_barrier(0);
    }
#undef STAGE

    // ---- reduce over the 16 code-lanes (first-min tie-break, butterfly)
    #pragma unroll
    for (int off = 8; off >= 1; off >>= 1) {
        #pragma unroll
        for (int i = 0; i < 4; ++i) {
            float ov = __shfl_xor(minv[i], off, 64);
            int   oi = __shfl_xor(mini[i], off, 64);
            if (ov < minv[i] || (ov == minv[i] && oi < mini[i])) {
                minv[i] = ov; mini[i] = oi;
            }
        }
    }

    // ---- publish: wave covers rows rg*16 + lk*4 + i (lanes lr==0)
    if (lr == 0) {
        #pragma unroll
        for (int i = 0; i < 4; ++i) {
            mvs[kg][rg * 16 + lk * 4 + i] = minv[i];
            mis[kg][rg * 16 + lk * 4 + i] = mini[i];
        }
    }
    if (kg == 0 && l < 16) fxn[rg * 16 + l] = xn;
    __syncthreads();

    // ---- merge kg halves + gather E[idx] -> outq (wave w: rows [w*8,+8))
    #pragma unroll
    for (int rr = 0; rr < 8; ++rr) {
        const int r = w * 8 + rr;
        // kg0 indices < kg1 indices: strict < keeps first-occurrence min
        const int idx = (mvs[1][r] < mvs[0][r]) ? mis[1][r] : mis[0][r];
        const float4 qv = *reinterpret_cast<const float4*>(
            E + (size_t)idx * D_DIM + l * 4);
        f32x4 tv = {qv.x, qv.y, qv.z, qv.w};
        __builtin_nontemporal_store(
            tv, reinterpret_cast<f32x4*>(outq + (size_t)(row0 + r) * D_DIM + l * 4));
    }

    // ---- loss partial: wave 0 sums (minval + xnorm) over the 32 rows
    if (w == 0) {
        float v = (l < BLOCK_ROWS) ? (fminf(mvs[0][l], mvs[1][l]) + fxn[l]) : 0.0f;
        #pragma unroll
        for (int off = 32; off; off >>= 1) v += __shfl_xor(v, off, 64);
        if (l == 0) lpart[blockIdx.x] = v;
    }
}

// ---------------------------------------------------------------- finalize
// deterministic fold of 1024 block partials -> vq_loss scalar
__global__ __launch_bounds__(256) void vq_finalize(const float* __restrict__ partials,
                                                   float* __restrict__ out_loss) {
    __shared__ float s[256];
    int t = threadIdx.x;
    s[t] = partials[t] + partials[t + 256] + partials[t + 512] + partials[t + 768];
    __syncthreads();
    #pragma unroll
    for (int off = 128; off; off >>= 1) {
        if (t < off) s[t] += s[t + off];
        __syncthreads();
    }
    if (t == 0)
        out_loss[0] = s[0] * (1.25f / (float)((size_t)N_ROWS * D_DIM));
}

// ---------------------------------------------------------------- launch
extern "C" void kernel_launch(void* const* d_in, const int* in_sizes, int n_in,
                              void* d_out, int out_size, void* d_ws, size_t ws_size,
                              hipStream_t stream) {
    const float* X = (const float*)d_in[0];   // latents  [32768, 256] f32
    const float* E = (const float*)d_in[1];   // codebook [1024, 256]  f32
    float* out = (float*)d_out;               // 8388608 quantized + 1 loss

    float* enorm = (float*)d_ws;                          // 1024 f32
    float* lpart = enorm + K_CODES;                       // 1024 f32
    i64*   Eb8   = (i64*)(lpart + 1024);                  // 256 KB fp8 frags

    vq_prep    <<<256,  256, 0, stream>>>(E, enorm, Eb8);
    vq_main    <<<NBLK, 256, 0, stream>>>(X, E, enorm, Eb8, out, lpart);
    vq_finalize<<<1,    256, 0, stream>>>(lpart, out + (size_t)N_ROWS * D_DIM);
}